// Round 1
// baseline (341.119 us; speedup 1.0000x reference)
//
#include <hip/hip_runtime.h>

// RBFolution: out[b,y,x,f] = exp(-beta[f] * (||patch||^2 - 2 patch.ccs[:,f] + ||ccs[:,f]||^2))
// x: [32,112,112,32] f32, ccs: [288,128] f32, beta: [128] f32, out: [32,110,110,128] f32
//
// bf16 MFMA implicit GEMM; p_sq/c_sq fp32-exact (only cross term bf16, err ~1e-5).
// R5: 3 output rows/block (staged 5), LDS 40.1 KB -> 4 blocks/CU (16 waves, was 12):
// main was latency/overlap-bound (~2.2 TB/s achieved vs 6.3 achievable), not pipe-bound.
// __launch_bounds__(256,4) caps VGPR at 128; c_sq/beta loads moved into the per-row
// epilogue to cut persistent register pressure. Refetch 1.5x->1.67x (+1.4 us) is the cost.

typedef __attribute__((ext_vector_type(8))) short bf16x8;
typedef __attribute__((ext_vector_type(4))) float f32x4;

#define HH 112
#define WW 112
#define CC 32
#define HO 110
#define WO 110
#define NF 128
#define KD 288
#define RPX 114        // pixels per staged row in LDS (reads reach px 113)
#define XP 32          // bf16 elems per pixel (64 B): b128 frag reads spread uniformly over banks
#define SROWS 5        // staged input rows per block
#define ORPB 3         // output rows per block

__device__ __forceinline__ unsigned short f32_to_bf16(float f) {
    unsigned u = __float_as_uint(f);
    unsigned r = u + 0x7FFFu + ((u >> 16) & 1u);   // round-to-nearest-even
    return (unsigned short)(r >> 16);
}

// --- Prologue: ccs [288][128] f32 -> ccs_t [128][288] bf16 (all blocks);
//     block 0 threads 0..127 also compute c_sq[f] = sum_d ccs[d][f]^2 (coalesced column walk).
__global__ __launch_bounds__(256) void rbf_prologue(const float* __restrict__ ccs,
                                                    unsigned short* __restrict__ ccs_t,
                                                    float* __restrict__ c_sq) {
    int idx = blockIdx.x * 256 + threadIdx.x;     // 0..36863, coalesced read
    int d = idx >> 7;
    int f = idx & 127;
    ccs_t[f * KD + d] = f32_to_bf16(ccs[idx]);
    if (blockIdx.x == 0 && threadIdx.x < 128) {
        const int fc = threadIdx.x;
        float s = 0.f;
        #pragma unroll 8
        for (int dd = 0; dd < KD; ++dd) {
            float v = ccs[dd * NF + fc];
            s += v * v;
        }
        c_sq[fc] = s;
    }
}

// --- Main: one block per (3-row strip, b). 3 output rows, 5 staged input rows.
__global__ __launch_bounds__(256, 4) void rbf_main(const float* __restrict__ x,
                                                   const unsigned short* __restrict__ ccs_t,
                                                   const float* __restrict__ c_sq,
                                                   const float* __restrict__ beta,
                                                   float* __restrict__ out) {
    __shared__ unsigned short xs[SROWS * RPX * XP];   // 36480 B
    __shared__ float colsum[564];                     // 5 rows x 112 cols (stride 112) + overrun pad
    __shared__ float p_sq[ORPB * 112];                // 1344 B  -> 40.1 KB total, 4 blocks/CU

    const int t = threadIdx.x;
    const int y0 = blockIdx.x * ORPB;  // 0,3,...,108
    const int b = blockIdx.y;          // 0..31
    const int rows = (HO - y0 < ORPB) ? (HO - y0) : ORPB;   // 3, or 2 for the tail strip

    // Stage x[y0..y0+4][0..111][0..31] -> LDS bf16; colsum from fp32 (exact p_sq).
    // 4480 float4 units = 17.5 * 256 (last iteration half, wave-uniform guard).
    // Row index clamped to 111 (clamped row feeds only unused/masked outputs).
    #pragma unroll
    for (int p = 0; p < 18; ++p) {
        int idx = t + p * 256;
        if (idx < SROWS * 112 * 8) {
            int q = idx & 7;              // channel quarter (4 floats)
            int ic = idx >> 3;            // 0..559 = i*112 + col
            int col = ic % 112;
            int i = ic / 112;
            int yg = y0 + i; if (yg > HH - 1) yg = HH - 1;
            const float4 v = *(const float4*)(x + ((size_t)(b * HH + yg) * WW + col) * CC + q * 4);
            unsigned short h0 = f32_to_bf16(v.x), h1 = f32_to_bf16(v.y);
            unsigned short h2 = f32_to_bf16(v.z), h3 = f32_to_bf16(v.w);
            uint2 pk;
            pk.x = (unsigned)h0 | ((unsigned)h1 << 16);
            pk.y = (unsigned)h2 | ((unsigned)h3 << 16);
            *(uint2*)(&xs[(i * RPX + col) * XP + q * 4]) = pk;   // 8B, contiguous per wave
            float part = v.x * v.x + v.y * v.y + v.z * v.z + v.w * v.w;
            part += __shfl_xor(part, 1);
            part += __shfl_xor(part, 2);
            part += __shfl_xor(part, 4);
            if (q == 0) colsum[ic] = part;   // stride 112
        }
    }
    __syncthreads();

    #pragma unroll
    for (int pp = 0; pp < 2; ++pp) {
        int idx = t + pp * 256;
        if (idx < ORPB * 112) {
            int r = idx / 112;
            int c = idx - r * 112;
            float s = 0.f;
            #pragma unroll
            for (int i = 0; i < 3; ++i)
                #pragma unroll
                for (int j = 0; j < 3; ++j)
                    s += colsum[(r + i) * 112 + c + j];   // c>=110 reads pad garbage -> masked px only
            p_sq[idx] = s;
        }
    }
    __syncthreads();

    const int lane  = t & 63;
    const int wave  = t >> 6;            // 4 waves x 32 filters
    const int laneM = lane & 15;
    const int quad  = lane >> 4;

    // A = ccs (M = filters): lane's filter-in-tile = laneM
    const unsigned short* ap0 = ccs_t + (size_t)(wave * 32 + laneM) * KD + quad * 8;
    const unsigned short* ap1 = ap0 + 16 * KD;

    // per-lane 4 consecutive filters (rows of D): f = wave*32 + ft*16 + quad*4 + e
    const int fb = wave * 32 + quad * 4;

    for (int r = 0; r < rows; ++r) {
        f32x4 acc[7][2];
        #pragma unroll
        for (int mi = 0; mi < 7; ++mi) {
            acc[mi][0] = (f32x4){0.f, 0.f, 0.f, 0.f};
            acc[mi][1] = (f32x4){0.f, 0.f, 0.f, 0.f};
        }

        #pragma unroll
        for (int kb = 0; kb < 9; ++kb) {     // one k-block per tap (ki,kj), K=32 channels
            const int ki = kb / 3, kj = kb % 3;
            bf16x8 a0 = *(const bf16x8*)(ap0 + kb * 32);
            bf16x8 a1 = *(const bf16x8*)(ap1 + kb * 32);
            #pragma unroll
            for (int mi = 0; mi < 7; ++mi) {
                // B[k = quad*8+j][n = laneM]: pixel px = mi*16+laneM+kj, staged row r+ki
                const bf16x8 bf = *(const bf16x8*)(&xs[((r + ki) * RPX + mi * 16 + laneM + kj) * XP + quad * 8]);
                acc[mi][0] = __builtin_amdgcn_mfma_f32_16x16x32_bf16(a0, bf, acc[mi][0], 0, 0, 0);
                acc[mi][1] = __builtin_amdgcn_mfma_f32_16x16x32_bf16(a1, bf, acc[mi][1], 0, 0, 0);
            }
        }

        // Epilogue: D[row = filter (quad*4+e)][col = pixel (laneM)] -> float4 stores along filters.
        // c_sq/beta loaded here (L1-hot) rather than held across the MFMA phase: saves 16 VGPRs.
        const float4 cs0 = *(const float4*)(c_sq + fb);
        const float4 cs1 = *(const float4*)(c_sq + fb + 16);
        const float4 bt0 = *(const float4*)(beta + fb);
        const float4 bt1 = *(const float4*)(beta + fb + 16);
        float* orow = out + (size_t)((b * HO + y0 + r) * WO) * NF;
        #pragma unroll
        for (int mi = 0; mi < 7; ++mi) {
            const int px = mi * 16 + laneM;
            const float ps = p_sq[r * 112 + px];
            float* op = orow + (size_t)px * NF + fb;
            #pragma unroll
            for (int ft = 0; ft < 2; ++ft) {
                const float4 cs = ft ? cs1 : cs0;
                const float4 bt = ft ? bt1 : bt0;
                float4 o;
                o.x = __expf(-bt.x * (ps - 2.f * acc[mi][ft][0] + cs.x));
                o.y = __expf(-bt.y * (ps - 2.f * acc[mi][ft][1] + cs.y));
                o.z = __expf(-bt.z * (ps - 2.f * acc[mi][ft][2] + cs.z));
                o.w = __expf(-bt.w * (ps - 2.f * acc[mi][ft][3] + cs.w));
                if (px < WO)
                    *(float4*)(op + ft * 16) = o;
            }
        }
    }
}

extern "C" void kernel_launch(void* const* d_in, const int* in_sizes, int n_in,
                              void* d_out, int out_size, void* d_ws, size_t ws_size,
                              hipStream_t stream) {
    const float* x    = (const float*)d_in[0];
    const float* ccs  = (const float*)d_in[1];
    const float* beta = (const float*)d_in[2];
    float* out = (float*)d_out;

    unsigned short* ccs_t = (unsigned short*)d_ws;                              // 128*288 bf16
    float* c_sq = (float*)((char*)d_ws + 128 * KD * sizeof(unsigned short));    // 128 f32

    rbf_prologue<<<144, 256, 0, stream>>>(ccs, ccs_t, c_sq);
    rbf_main<<<dim3((HO + ORPB - 1) / ORPB, 32), 256, 0, stream>>>(x, ccs_t, c_sq, beta, out);
}

// Round 3
// 279.215 us; speedup vs baseline: 1.2217x; 1.2217x over previous
//
#include <hip/hip_runtime.h>

// RBFolution: out[b,y,x,f] = exp(-beta[f] * (||patch||^2 - 2 patch.ccs[:,f] + ||ccs[:,f]||^2))
// x: [32,112,112,32] f32, ccs: [288,128] f32, beta: [128] f32, out: [32,110,110,128] f32
//
// bf16 MFMA implicit GEMM; p_sq/c_sq fp32-exact (only cross term bf16, err ~1e-5).
// R7 = R6 with the nt-store builtin fed a clang ext_vector (f32x4) instead of HIP's
// float4 class (which __builtin_nontemporal_store rejects).
// R6 rationale: R5 counters showed FETCH=159.6MB (>=75MB unexplained) and WRITE=281MB
// vs 198MB actual -> partial-line write-allocate on out (two separate 64B stores per
// 128B line). nt stores stream out past L2/L3: kill the RFO fetch + pollution.
// R5 lesson: do NOT cap the register allocator (__launch_bounds__(256,4) -> VGPR=64 -> ILP collapse).

typedef __attribute__((ext_vector_type(8))) short bf16x8;
typedef __attribute__((ext_vector_type(4))) float f32x4;

#define HH 112
#define WW 112
#define CC 32
#define HO 110
#define WO 110
#define NF 128
#define KD 288
#define RPX 114        // pixels per staged row in LDS (reads reach px 113)
#define XP 32          // bf16 elems per pixel (64 B): b128 frag reads spread uniformly over banks

__device__ __forceinline__ unsigned short f32_to_bf16(float f) {
    unsigned u = __float_as_uint(f);
    unsigned r = u + 0x7FFFu + ((u >> 16) & 1u);   // round-to-nearest-even
    return (unsigned short)(r >> 16);
}

// --- Prologue: ccs [288][128] f32 -> ccs_t [128][288] bf16 (all blocks);
//     block 0 threads 0..127 also compute c_sq[f] = sum_d ccs[d][f]^2 (coalesced column walk).
__global__ __launch_bounds__(256) void rbf_prologue(const float* __restrict__ ccs,
                                                    unsigned short* __restrict__ ccs_t,
                                                    float* __restrict__ c_sq) {
    int idx = blockIdx.x * 256 + threadIdx.x;     // 0..36863, coalesced read
    int d = idx >> 7;
    int f = idx & 127;
    ccs_t[f * KD + d] = f32_to_bf16(ccs[idx]);
    if (blockIdx.x == 0 && threadIdx.x < 128) {
        const int fc = threadIdx.x;
        float s = 0.f;
        #pragma unroll 8
        for (int dd = 0; dd < KD; ++dd) {
            float v = ccs[dd * NF + fc];
            s += v * v;
        }
        c_sq[fc] = s;
    }
}

// --- Main: one block per (4-row strip, b). 4 output rows, 6 staged input rows.
__global__ __launch_bounds__(256) void rbf_main(const float* __restrict__ x,
                                                const unsigned short* __restrict__ ccs_t,
                                                const float* __restrict__ c_sq,
                                                const float* __restrict__ beta,
                                                float* __restrict__ out) {
    __shared__ unsigned short xs[6 * RPX * XP];    // 43776 B
    __shared__ float colsum[676];                   // 6 rows x 112 cols (stride 112) + overrun pad
    __shared__ float p_sq[4 * 112];

    const int t = threadIdx.x;
    const int y0 = blockIdx.x * 4;  // 0,4,...,108
    const int b = blockIdx.y;       // 0..31
    const int rows = (HO - y0 < 4) ? (HO - y0) : 4;   // 4, or 2 for the tail strip

    // Stage x[y0..y0+5][0..111][0..31] -> LDS bf16; colsum from fp32 (exact p_sq).
    // 5376 float4 units = 21 * 256 exactly (no tail). Row index clamped to 111
    // (clamped rows feed only masked outputs).
    #pragma unroll
    for (int p = 0; p < 21; ++p) {
        int idx = t + p * 256;
        int q = idx & 7;              // channel quarter (4 floats)
        int ic = idx >> 3;            // 0..671 = i*112 + col
        int col = ic % 112;
        int i = ic / 112;
        int yg = y0 + i; if (yg > HH - 1) yg = HH - 1;
        const float4 v = *(const float4*)(x + ((size_t)(b * HH + yg) * WW + col) * CC + q * 4);
        unsigned short h0 = f32_to_bf16(v.x), h1 = f32_to_bf16(v.y);
        unsigned short h2 = f32_to_bf16(v.z), h3 = f32_to_bf16(v.w);
        uint2 pk;
        pk.x = (unsigned)h0 | ((unsigned)h1 << 16);
        pk.y = (unsigned)h2 | ((unsigned)h3 << 16);
        *(uint2*)(&xs[(i * RPX + col) * XP + q * 4]) = pk;   // 8B, contiguous 512B per wave
        float part = v.x * v.x + v.y * v.y + v.z * v.z + v.w * v.w;
        part += __shfl_xor(part, 1);
        part += __shfl_xor(part, 2);
        part += __shfl_xor(part, 4);
        if (q == 0) colsum[ic] = part;   // stride 112
    }
    __syncthreads();

    #pragma unroll
    for (int pp = 0; pp < 2; ++pp) {
        int idx = t + pp * 256;
        if (idx < 448) {
            int r = idx / 112;
            int c = idx - r * 112;
            float s = 0.f;
            #pragma unroll
            for (int i = 0; i < 3; ++i)
                #pragma unroll
                for (int j = 0; j < 3; ++j)
                    s += colsum[(r + i) * 112 + c + j];   // c>=110 reads pad garbage -> masked px only
            p_sq[idx] = s;
        }
    }
    __syncthreads();

    const int lane  = t & 63;
    const int wave  = t >> 6;            // 4 waves x 32 filters
    const int laneM = lane & 15;
    const int quad  = lane >> 4;

    // A = ccs (M = filters): lane's filter-in-tile = laneM
    const unsigned short* ap0 = ccs_t + (size_t)(wave * 32 + laneM) * KD + quad * 8;
    const unsigned short* ap1 = ap0 + 16 * KD;

    // per-lane 4 consecutive filters (rows of D): f = wave*32 + ft*16 + quad*4 + e
    const int fb = wave * 32 + quad * 4;
    const float4 cs0 = *(const float4*)(c_sq + fb);
    const float4 cs1 = *(const float4*)(c_sq + fb + 16);
    const float4 bt0 = *(const float4*)(beta + fb);
    const float4 bt1 = *(const float4*)(beta + fb + 16);

    for (int r = 0; r < rows; ++r) {
        f32x4 acc[7][2];
        #pragma unroll
        for (int mi = 0; mi < 7; ++mi) {
            acc[mi][0] = (f32x4){0.f, 0.f, 0.f, 0.f};
            acc[mi][1] = (f32x4){0.f, 0.f, 0.f, 0.f};
        }

        #pragma unroll
        for (int kb = 0; kb < 9; ++kb) {     // one k-block per tap (ki,kj), K=32 channels
            const int ki = kb / 3, kj = kb % 3;
            bf16x8 a0 = *(const bf16x8*)(ap0 + kb * 32);
            bf16x8 a1 = *(const bf16x8*)(ap1 + kb * 32);
            #pragma unroll
            for (int mi = 0; mi < 7; ++mi) {
                // B[k = quad*8+j][n = laneM]: pixel px = mi*16+laneM+kj, staged row r+ki
                const bf16x8 bf = *(const bf16x8*)(&xs[((r + ki) * RPX + mi * 16 + laneM + kj) * XP + quad * 8]);
                acc[mi][0] = __builtin_amdgcn_mfma_f32_16x16x32_bf16(a0, bf, acc[mi][0], 0, 0, 0);
                acc[mi][1] = __builtin_amdgcn_mfma_f32_16x16x32_bf16(a1, bf, acc[mi][1], 0, 0, 0);
            }
        }

        // Epilogue: D[row = filter (quad*4+e)][col = pixel (laneM)] -> float4 stores along filters.
        // NON-TEMPORAL: out is write-once, never read; nt avoids write-allocate RFO
        // (R5 counters: FETCH +75MB, WRITE 1.42x) and L2/L3 pollution.
        float* orow = out + (size_t)((b * HO + y0 + r) * WO) * NF;
        #pragma unroll
        for (int mi = 0; mi < 7; ++mi) {
            const int px = mi * 16 + laneM;
            const float ps = p_sq[r * 112 + px];
            float* op = orow + (size_t)px * NF + fb;
            #pragma unroll
            for (int ft = 0; ft < 2; ++ft) {
                const float4 cs = ft ? cs1 : cs0;
                const float4 bt = ft ? bt1 : bt0;
                f32x4 o;
                o[0] = __expf(-bt.x * (ps - 2.f * acc[mi][ft][0] + cs.x));
                o[1] = __expf(-bt.y * (ps - 2.f * acc[mi][ft][1] + cs.y));
                o[2] = __expf(-bt.z * (ps - 2.f * acc[mi][ft][2] + cs.z));
                o[3] = __expf(-bt.w * (ps - 2.f * acc[mi][ft][3] + cs.w));
                if (px < WO)
                    __builtin_nontemporal_store(o, (f32x4*)(op + ft * 16));
            }
        }
    }
}

extern "C" void kernel_launch(void* const* d_in, const int* in_sizes, int n_in,
                              void* d_out, int out_size, void* d_ws, size_t ws_size,
                              hipStream_t stream) {
    const float* x    = (const float*)d_in[0];
    const float* ccs  = (const float*)d_in[1];
    const float* beta = (const float*)d_in[2];
    float* out = (float*)d_out;

    unsigned short* ccs_t = (unsigned short*)d_ws;                              // 128*288 bf16
    float* c_sq = (float*)((char*)d_ws + 128 * KD * sizeof(unsigned short));    // 128 f32

    rbf_prologue<<<144, 256, 0, stream>>>(ccs, ccs_t, c_sq);
    rbf_main<<<dim3(28, 32), 256, 0, stream>>>(x, ccs_t, c_sq, beta, out);
}